// Round 1
// baseline (593.078 us; speedup 1.0000x reference)
//
#include <hip/hip_runtime.h>
#include <hip/hip_cooperative_groups.h>

namespace cg = cooperative_groups;

// Problem dims (fixed by reference setup_inputs)
#define N_DOCS   4096
#define N_WORDS  10000
#define N_TOPICS 100
#define EDIM     384

// Sinkhorn partial-buffer stride per ping-pong phase (floats)
#define PSTRIDE  10240u

// ---------------- workspace layout (float offsets; first 8 floats = 4 doubles) ----
// doubles: dscal[0]=loss_DT, dscal[1]=loss_TW, dscal[2]=sum(bow*log(recon)), dscal[3] unused
#define OFF_KDT   8u                         // 4096*100
#define OFF_KTW   (OFF_KDT + 409600u)        // 100*10000
#define OFF_THETA (OFF_KTW + 1000000u)       // 4096*100
#define OFF_BETA  (OFF_THETA + 409600u)      // 100*10000
#define OFF_BDT   (OFF_BETA + 1000000u)      // 100 (pad 128)
#define OFF_BTW   (OFF_BDT + 128u)           // 10000 (pad 10016)
#define OFF_ND    (OFF_BTW + 10016u)         // 4096
#define OFF_NW    (OFF_ND + 4096u)           // 10000
#define OFF_NT    (OFF_NW + 10000u)          // 100 (pad 128)
#define OFF_PART  (OFF_NT + 128u)            // 2 * PSTRIDE
// total ~2.87M floats ~11.5 MB

__device__ __forceinline__ float block_reduce_sum_256(float v, volatile float* sh) {
#pragma unroll
  for (int off = 32; off > 0; off >>= 1) v += __shfl_down(v, off, 64);
  __syncthreads();
  if ((threadIdx.x & 63) == 0) sh[threadIdx.x >> 6] = v;
  __syncthreads();
  return sh[0] + sh[1] + sh[2] + sh[3];
}

__device__ __forceinline__ float block_reduce_max_256(float v, volatile float* sh) {
#pragma unroll
  for (int off = 32; off > 0; off >>= 1) v = fmaxf(v, __shfl_down(v, off, 64));
  __syncthreads();
  if ((threadIdx.x & 63) == 0) sh[threadIdx.x >> 6] = v;
  __syncthreads();
  return fmaxf(fmaxf(sh[0], sh[1]), fmaxf(sh[2], sh[3]));
}

// ---------------- row-norm kernel: ||x||^2 for docs / words / topics ----------------
__global__ __launch_bounds__(64)
void norms_kernel(const float* __restrict__ docs, const float* __restrict__ words,
                  const float* __restrict__ topics, float* __restrict__ nd,
                  float* __restrict__ nw, float* __restrict__ nt) {
  int row = blockIdx.x;  // 0..14195
  const float* src; float* dst; int r;
  if (row < N_DOCS)                { src = docs;   r = row;                  dst = nd; }
  else if (row < N_DOCS + N_WORDS) { src = words;  r = row - N_DOCS;         dst = nw; }
  else                             { src = topics; r = row - N_DOCS - N_WORDS; dst = nt; }
  int tid = threadIdx.x;
  float s = 0.f;
  for (int k = tid; k < EDIM; k += 64) { float x = src[r * EDIM + k]; s += x * x; }
#pragma unroll
  for (int off = 32; off > 0; off >>= 1) s += __shfl_down(s, off, 64);
  if (tid == 0) dst[r] = s;
}

// ---------------- softmax(b) for both marginals + zero the loss accumulators --------
__global__ __launch_bounds__(256)
void prep_kernel(const float* __restrict__ topic_w, const float* __restrict__ word_w,
                 float* __restrict__ b_dt, float* __restrict__ b_tw,
                 double* __restrict__ dscal) {
  __shared__ float sh[4];
  int tid = threadIdx.x;
  // topics (100)
  float m = -3.0e38f;
  for (int i = tid; i < N_TOPICS; i += 256) m = fmaxf(m, topic_w[i]);
  m = block_reduce_max_256(m, sh);
  float s = 0.f;
  for (int i = tid; i < N_TOPICS; i += 256) s += __expf(topic_w[i] - m);
  s = block_reduce_sum_256(s, sh);
  float inv = 1.0f / s;
  for (int i = tid; i < N_TOPICS; i += 256) b_dt[i] = __expf(topic_w[i] - m) * inv;
  // words (10000)
  float m2 = -3.0e38f;
  for (int i = tid; i < N_WORDS; i += 256) m2 = fmaxf(m2, word_w[i]);
  m2 = block_reduce_max_256(m2, sh);
  float s2 = 0.f;
  for (int i = tid; i < N_WORDS; i += 256) s2 += __expf(word_w[i] - m2);
  s2 = block_reduce_sum_256(s2, sh);
  float inv2 = 1.0f / s2;
  for (int i = tid; i < N_WORDS; i += 256) b_tw[i] = __expf(word_w[i] - m2) * inv2;
  if (tid < 4) dscal[tid] = 0.0;
}

// ---------------- K = exp(-alpha * (||a||^2 + ||b||^2 - 2 a.b)) --------------------
// 64x64 output tile, 256 threads, 4x4 per thread, k-chunks of 16 staged in LDS.
__global__ __launch_bounds__(256)
void dist_exp_kernel(const float* __restrict__ A, const float* __restrict__ B,
                     const float* __restrict__ nA, const float* __restrict__ nB,
                     float* __restrict__ Kout, int nI, int nJ, float alpha) {
  __shared__ __align__(16) float As[16][64];  // [k][i]
  __shared__ __align__(16) float Bs[16][64];  // [k][j]
  const int i0 = blockIdx.y * 64, j0 = blockIdx.x * 64;
  const int tid = threadIdx.x;
  const int r = tid & 63, kg = tid >> 6;   // staging map: row r, k-group kg (0..3)
  const int tx = tid & 15, ty = tid >> 4;  // compute map
  float acc[4][4] = {};
  for (int k0 = 0; k0 < EDIM; k0 += 16) {
    float4 av = make_float4(0.f, 0.f, 0.f, 0.f);
    float4 bv = make_float4(0.f, 0.f, 0.f, 0.f);
    int gi = i0 + r, gj = j0 + r;
    if (gi < nI) av = *reinterpret_cast<const float4*>(&A[gi * EDIM + k0 + kg * 4]);
    if (gj < nJ) bv = *reinterpret_cast<const float4*>(&B[gj * EDIM + k0 + kg * 4]);
    As[kg * 4 + 0][r] = av.x; As[kg * 4 + 1][r] = av.y;
    As[kg * 4 + 2][r] = av.z; As[kg * 4 + 3][r] = av.w;
    Bs[kg * 4 + 0][r] = bv.x; Bs[kg * 4 + 1][r] = bv.y;
    Bs[kg * 4 + 2][r] = bv.z; Bs[kg * 4 + 3][r] = bv.w;
    __syncthreads();
#pragma unroll
    for (int kk = 0; kk < 16; ++kk) {
      float4 a4 = *reinterpret_cast<const float4*>(&As[kk][ty * 4]);
      float4 b4 = *reinterpret_cast<const float4*>(&Bs[kk][tx * 4]);
      float aa[4] = {a4.x, a4.y, a4.z, a4.w};
      float bb[4] = {b4.x, b4.y, b4.z, b4.w};
#pragma unroll
      for (int di = 0; di < 4; ++di)
#pragma unroll
        for (int dj = 0; dj < 4; ++dj) acc[di][dj] += aa[di] * bb[dj];
    }
    __syncthreads();
  }
#pragma unroll
  for (int di = 0; di < 4; ++di) {
    int gi = i0 + ty * 4 + di;
    if (gi < nI) {
      float na = nA[gi];
#pragma unroll
      for (int dj = 0; dj < 4; ++dj) {
        int gj = j0 + tx * 4 + dj;
        if (gj < nJ)
          Kout[(size_t)gi * nJ + gj] = __expf(-alpha * (na + nB[gj] - 2.f * acc[di][dj]));
      }
    }
  }
}

// ---------------- Sinkhorn doc-topic: rows=4096 partitioned over 64 blocks ----------
// Per iteration: colsum = K^T u needs cross-block reduce (1 grid.sync, ping-pong partials).
__global__ __launch_bounds__(256)
void sinkhorn_dt_kernel(const float* __restrict__ Kg, const float* __restrict__ b,
                        float* __restrict__ part, float* __restrict__ theta,
                        double* __restrict__ dscal) {
  cg::grid_group grid = cg::this_grid();
  __shared__ float Kl[64 * 100];
  __shared__ float u_l[64];
  __shared__ float v_l[100];
  __shared__ float cs[100];
  __shared__ float bl[100];
  __shared__ float err_sh;
  __shared__ float sh4[4];
  const int tid = threadIdx.x;
  const int blk = blockIdx.x;      // 64 blocks
  const int r0 = blk * 64;
  for (int idx = tid; idx < 6400; idx += 256) Kl[idx] = Kg[r0 * 100 + idx];
  if (tid < 100) bl[tid] = b[tid];
  if (tid < 64) u_l[tid] = 1.0f / 4096.0f;
  __syncthreads();
  int cpt = 0, p = 0;
  float err = 1.0f;
  while (true) {
    // partial colsum over this block's 64 rows (current u)
    if (tid < 100) {
      float s = 0.f;
      for (int r2 = 0; r2 < 64; ++r2) s += Kl[r2 * 100 + tid] * u_l[r2];
      part[p * PSTRIDE + blk * 100 + tid] = s;
    }
    grid.sync();
    if (tid < 100) {
      float c = 0.f;
      for (int bb = 0; bb < 64; ++bb) c += part[p * PSTRIDE + bb * 100 + tid];
      v_l[tid] = bl[tid] / (c + 1e-16f);
    }
    p ^= 1;
    __syncthreads();
    if (tid < 64) {
      float d = 0.f;
      for (int j = 0; j < 100; ++j) d += Kl[tid * 100 + j] * v_l[j];
      u_l[tid] = (1.0f / 4096.0f) / (d + 1e-16f);
    }
    __syncthreads();
    ++cpt;
    if (cpt % 50 == 1) {  // err = sum |v * (K^T u_new) - b|
      if (tid < 100) {
        float s = 0.f;
        for (int r2 = 0; r2 < 64; ++r2) s += Kl[r2 * 100 + tid] * u_l[r2];
        part[p * PSTRIDE + blk * 100 + tid] = s;
      }
      grid.sync();
      if (tid < 100) {
        float c = 0.f;
        for (int bb = 0; bb < 64; ++bb) c += part[p * PSTRIDE + bb * 100 + tid];
        cs[tid] = c;
      }
      p ^= 1;
      __syncthreads();
      if (tid == 0) {
        float e = 0.f;
        for (int j = 0; j < 100; ++j) e += fabsf(v_l[j] * cs[j] - bl[j]);
        err_sh = e;
      }
      __syncthreads();
      err = err_sh;  // identical in every block (same deterministic arithmetic)
    }
    if (!(err > 0.005f && cpt < 5000)) break;
  }
  // theta = N * u.K.v ; loss_DT = sum(transp * M), M = -log(K)/alpha
  float lp = 0.f;
  for (int idx = tid; idx < 6400; idx += 256) {
    int r2 = idx / 100, j = idx - r2 * 100;
    float kv = Kl[idx];
    float t = u_l[r2] * kv * v_l[j];
    lp += t * (-__logf(kv) * (1.0f / 3.0f));
    theta[(size_t)r0 * 100 + idx] = 4096.0f * t;
  }
  lp = block_reduce_sum_256(lp, sh4);
  if (tid == 0) atomicAdd(&dscal[0], (double)lp);
}

// ---------------- Sinkhorn topic-word: cols=10000 partitioned over 100 blocks -------
__global__ __launch_bounds__(256)
void sinkhorn_tw_kernel(const float* __restrict__ Kg, const float* __restrict__ b,
                        float* __restrict__ part, float* __restrict__ beta,
                        double* __restrict__ dscal) {
  cg::grid_group grid = cg::this_grid();
  __shared__ float Kl[100 * 100];   // 40 KB: [topic][local col]
  __shared__ float u_l[100];
  __shared__ float v_l[100];
  __shared__ float bl[100];
  __shared__ float earr[100];
  __shared__ float err_sh;
  __shared__ float sh4[4];
  const int tid = threadIdx.x;
  const int blk = blockIdx.x;      // 100 blocks
  const int j0 = blk * 100;
  for (int idx = tid; idx < 10000; idx += 256) {
    int i = idx / 100, jl = idx - i * 100;
    Kl[idx] = Kg[(size_t)i * N_WORDS + j0 + jl];
  }
  if (tid < 100) { bl[tid] = b[j0 + tid]; u_l[tid] = 0.01f; }
  __syncthreads();
  int cpt = 0, p = 0;
  float err = 1.0f;
  while (true) {
    // v update: block-local (u replicated)
    if (tid < 100) {
      float s = 0.f;
      for (int i = 0; i < 100; ++i) s += Kl[i * 100 + tid] * u_l[i];
      v_l[tid] = bl[tid] / (s + 1e-16f);
    }
    __syncthreads();
    // u update: rowsum needs cross-block reduce
    if (tid < 100) {
      float d = 0.f;
      for (int jl = 0; jl < 100; ++jl) d += Kl[tid * 100 + jl] * v_l[jl];
      part[p * PSTRIDE + blk * 100 + tid] = d;
    }
    grid.sync();
    if (tid < 100) {
      float rs = 0.f;
      for (int bb = 0; bb < 100; ++bb) rs += part[p * PSTRIDE + bb * 100 + tid];
      u_l[tid] = 0.01f / (rs + 1e-16f);
    }
    p ^= 1;
    __syncthreads();
    ++cpt;
    if (cpt % 50 == 1) {
      if (tid < 100) {
        float s = 0.f;
        for (int i = 0; i < 100; ++i) s += Kl[i * 100 + tid] * u_l[i];
        earr[tid] = fabsf(v_l[tid] * s - bl[tid]);
      }
      __syncthreads();
      if (tid == 0) {
        float e = 0.f;
        for (int jl = 0; jl < 100; ++jl) e += earr[jl];
        part[p * PSTRIDE + blk * 100] = e;
      }
      grid.sync();
      if (tid == 0) {
        float e = 0.f;
        for (int bb = 0; bb < 100; ++bb) e += part[p * PSTRIDE + bb * 100];
        err_sh = e;
      }
      p ^= 1;
      __syncthreads();
      err = err_sh;
    }
    if (!(err > 0.005f && cpt < 5000)) break;
  }
  // beta = K_topics * u.K.v ; loss_TW = sum(transp * M), M = -log(K)/alpha
  float lp = 0.f;
  for (int idx = tid; idx < 10000; idx += 256) {
    int i = idx / 100, jl = idx - i * 100;
    float kv = Kl[idx];
    float t = u_l[i] * kv * v_l[jl];
    lp += t * (-__logf(kv) * 0.5f);
    beta[(size_t)i * N_WORDS + j0 + jl] = 100.0f * t;
  }
  lp = block_reduce_sum_256(lp, sh4);
  if (tid == 0) atomicAdd(&dscal[1], (double)lp);
}

// ---------------- fused recon = theta @ beta ; acc += bow * log(recon + eps) -------
// 128x128 tile, 8x8 per thread, K staged in 2 chunks of 50 (LDS 51.2 KB)
#define RTILE 128
#define CTILE 128
#define KCH   50
__global__ __launch_bounds__(256)
void recon_loss_kernel(const float* __restrict__ theta, const float* __restrict__ beta,
                       const float* __restrict__ bow, double* __restrict__ dscal) {
  __shared__ __align__(16) float th[KCH][RTILE];
  __shared__ __align__(16) float be[KCH][CTILE];
  __shared__ float sh4[4];
  const int r0 = blockIdx.y * RTILE, c0 = blockIdx.x * CTILE;
  const int tid = threadIdx.x;
  const int tx = tid & 15, ty = tid >> 4;
  float acc[8][8] = {};
  for (int kc = 0; kc < N_TOPICS; kc += KCH) {
    for (int idx = tid; idx < KCH * RTILE; idx += 256) {
      int rr = idx / KCH;
      int kk = idx - rr * KCH;
      th[kk][rr] = theta[(size_t)(r0 + rr) * 100 + kc + kk];
    }
    for (int idx = tid; idx < KCH * CTILE; idx += 256) {
      int kk = idx >> 7;
      int jj = idx & 127;
      int c = c0 + jj;
      be[kk][jj] = (c < N_WORDS) ? beta[(size_t)(kc + kk) * N_WORDS + c] : 0.f;
    }
    __syncthreads();
#pragma unroll 2
    for (int k = 0; k < KCH; ++k) {
      float a[8], b[8];
      *(float4*)&a[0] = *(const float4*)&th[k][ty * 8];
      *(float4*)&a[4] = *(const float4*)&th[k][ty * 8 + 4];
      *(float4*)&b[0] = *(const float4*)&be[k][tx * 8];
      *(float4*)&b[4] = *(const float4*)&be[k][tx * 8 + 4];
#pragma unroll
      for (int di = 0; di < 8; ++di)
#pragma unroll
        for (int dj = 0; dj < 8; ++dj) acc[di][dj] += a[di] * b[dj];
    }
    __syncthreads();
  }
  float lp = 0.f;
#pragma unroll
  for (int di = 0; di < 8; ++di) {
    int gi = r0 + ty * 8 + di;
    const float* bowrow = &bow[(size_t)gi * N_WORDS];
#pragma unroll
    for (int q4 = 0; q4 < 2; ++q4) {
      int gj = c0 + tx * 8 + q4 * 4;
      if (gj + 3 < N_WORDS) {
        float4 bw = *reinterpret_cast<const float4*>(&bowrow[gj]);
        lp += bw.x * __logf(acc[di][q4 * 4 + 0] + 1e-12f);
        lp += bw.y * __logf(acc[di][q4 * 4 + 1] + 1e-12f);
        lp += bw.z * __logf(acc[di][q4 * 4 + 2] + 1e-12f);
        lp += bw.w * __logf(acc[di][q4 * 4 + 3] + 1e-12f);
      } else {
        for (int q = 0; q < 4; ++q) {
          int g2 = gj + q;
          if (g2 < N_WORDS) lp += bowrow[g2] * __logf(acc[di][q4 * 4 + q] + 1e-12f);
        }
      }
    }
  }
  lp = block_reduce_sum_256(lp, sh4);
  if (tid == 0) atomicAdd(&dscal[2], (double)lp);
}

// ---------------- final scalar ------------------------------------------------------
__global__ void finalize_kernel(const double* __restrict__ dscal, float* __restrict__ out) {
  out[0] = (float)(dscal[0] + dscal[1] - dscal[2] * (1.0 / 4096.0));
}

extern "C" void kernel_launch(void* const* d_in, const int* in_sizes, int n_in,
                              void* d_out, int out_size, void* d_ws, size_t ws_size,
                              hipStream_t stream) {
  const float* bow     = (const float*)d_in[0];
  const float* docs    = (const float*)d_in[1];
  const float* words   = (const float*)d_in[2];
  const float* topics  = (const float*)d_in[3];
  const float* word_w  = (const float*)d_in[4];
  const float* topic_w = (const float*)d_in[5];
  float* out = (float*)d_out;

  double* dscal = (double*)d_ws;
  float* fws  = (float*)d_ws;
  float* Kdt  = fws + OFF_KDT;
  float* Ktw  = fws + OFF_KTW;
  float* theta = fws + OFF_THETA;
  float* beta  = fws + OFF_BETA;
  float* b_dt = fws + OFF_BDT;
  float* b_tw = fws + OFF_BTW;
  float* nd   = fws + OFF_ND;
  float* nw   = fws + OFF_NW;
  float* nt   = fws + OFF_NT;
  float* part = fws + OFF_PART;

  norms_kernel<<<dim3(N_DOCS + N_WORDS + N_TOPICS), dim3(64), 0, stream>>>(
      docs, words, topics, nd, nw, nt);
  prep_kernel<<<dim3(1), dim3(256), 0, stream>>>(topic_w, word_w, b_dt, b_tw, dscal);
  dist_exp_kernel<<<dim3(2, 64), dim3(256), 0, stream>>>(
      docs, topics, nd, nt, Kdt, N_DOCS, N_TOPICS, 3.0f);
  dist_exp_kernel<<<dim3(157, 2), dim3(256), 0, stream>>>(
      topics, words, nt, nw, Ktw, N_TOPICS, N_WORDS, 2.0f);

  {
    const float* a0 = Kdt; const float* a1 = b_dt; float* a2 = part; float* a3 = theta;
    double* a4 = dscal;
    void* args[] = {&a0, &a1, &a2, &a3, &a4};
    hipLaunchCooperativeKernel((void*)sinkhorn_dt_kernel, dim3(64), dim3(256), args, 0, stream);
  }
  {
    const float* a0 = Ktw; const float* a1 = b_tw; float* a2 = part; float* a3 = beta;
    double* a4 = dscal;
    void* args[] = {&a0, &a1, &a2, &a3, &a4};
    hipLaunchCooperativeKernel((void*)sinkhorn_tw_kernel, dim3(100), dim3(256), args, 0, stream);
  }

  recon_loss_kernel<<<dim3(79, 32), dim3(256), 0, stream>>>(theta, beta, bow, dscal);
  finalize_kernel<<<dim3(1), dim3(1), 0, stream>>>(dscal, out);

  (void)in_sizes; (void)n_in; (void)out_size; (void)ws_size;
}

// Round 2
// 548.896 us; speedup vs baseline: 1.0805x; 1.0805x over previous
//
#include <hip/hip_runtime.h>

// Problem dims (fixed by reference setup_inputs)
#define N_DOCS   4096
#define N_WORDS  10000
#define N_TOPICS 100
#define EDIM     384
#define KPAD     128      // padded inner dim for bf16 MFMA recon
#define BT_ROWS  10112    // beta^T rows allocated (79*128 grid cols)

// ---------------- workspace layout (float offsets) --------------------------------
// [0..8): 4 doubles: loss_DT, loss_TW, sum(bow*log(recon)), unused
// [8]: err_dt, [9]: err_tw
#define OFF_KDT   16u                        // 4096*100 fp32
#define OFF_KDTT  (OFF_KDT  + 409600u)       // 100*4096 fp32 (transpose)
#define OFF_KTW   (OFF_KDTT + 409600u)       // 100*10000 fp32
#define OFF_BDT   (OFF_KTW  + 1000000u)      // 100 (pad 128)
#define OFF_BTW   (OFF_BDT  + 128u)          // 10000 (pad 10016)
#define OFF_ND    (OFF_BTW  + 10016u)        // 4096
#define OFF_NW    (OFF_ND   + 4096u)         // 10000 (pad 10016)
#define OFF_NT    (OFF_NW   + 10016u)        // 100 (pad 128)
#define OFF_UDT   (OFF_NT   + 128u)          // 4096
#define OFF_VDT   (OFF_UDT  + 4096u)         // 100 (pad 128)
#define OFF_UTW   (OFF_VDT  + 128u)          // 100 (pad 128)
#define OFF_VTW   (OFF_UTW  + 128u)          // 10000 (pad 10016)
#define OFF_THB   (OFF_VTW  + 10016u)        // theta bf16 4096*128 = 262144 floats
#define OFF_BTT   (OFF_THB  + 262144u)       // beta^T bf16 10112*128 = 647168 floats
// total = OFF_BTT + 647168 = 2,767,280 floats ~= 10.6 MiB (less than round-1's 11.4)

typedef __attribute__((ext_vector_type(8))) short bf16x8;
typedef __attribute__((ext_vector_type(4))) float f32x4;

__device__ __forceinline__ float block_reduce_sum_256(float v, volatile float* sh) {
#pragma unroll
  for (int off = 32; off > 0; off >>= 1) v += __shfl_down(v, off, 64);
  __syncthreads();
  if ((threadIdx.x & 63) == 0) sh[threadIdx.x >> 6] = v;
  __syncthreads();
  return sh[0] + sh[1] + sh[2] + sh[3];
}

__device__ __forceinline__ float block_reduce_max_256(float v, volatile float* sh) {
#pragma unroll
  for (int off = 32; off > 0; off >>= 1) v = fmaxf(v, __shfl_down(v, off, 64));
  __syncthreads();
  if ((threadIdx.x & 63) == 0) sh[threadIdx.x >> 6] = v;
  __syncthreads();
  return fmaxf(fmaxf(sh[0], sh[1]), fmaxf(sh[2], sh[3]));
}

__device__ __forceinline__ unsigned short f2bf(float x) {
  union { float f; unsigned int u; } c; c.f = x;
  unsigned int r = c.u + 0x7FFF + ((c.u >> 16) & 1);   // RNE
  return (unsigned short)(r >> 16);
}

// ---------------- row-norm kernel: ||x||^2 for docs / words / topics ----------------
__global__ __launch_bounds__(64)
void norms_kernel(const float* __restrict__ docs, const float* __restrict__ words,
                  const float* __restrict__ topics, float* __restrict__ nd,
                  float* __restrict__ nw, float* __restrict__ nt) {
  int row = blockIdx.x;
  const float* src; float* dst; int r;
  if (row < N_DOCS)                { src = docs;   r = row;                    dst = nd; }
  else if (row < N_DOCS + N_WORDS) { src = words;  r = row - N_DOCS;           dst = nw; }
  else                             { src = topics; r = row - N_DOCS - N_WORDS; dst = nt; }
  int tid = threadIdx.x;
  float s = 0.f;
  for (int k = tid; k < EDIM; k += 64) { float x = src[r * EDIM + k]; s += x * x; }
#pragma unroll
  for (int off = 32; off > 0; off >>= 1) s += __shfl_down(s, off, 64);
  if (tid == 0) dst[r] = s;
}

// ---------------- softmax marginals + zero accumulators ----------------------------
__global__ __launch_bounds__(256)
void prep_kernel(const float* __restrict__ topic_w, const float* __restrict__ word_w,
                 float* __restrict__ b_dt, float* __restrict__ b_tw,
                 double* __restrict__ dscal, float* __restrict__ errs) {
  __shared__ float sh[4];
  int tid = threadIdx.x;
  float m = -3.0e38f;
  for (int i = tid; i < N_TOPICS; i += 256) m = fmaxf(m, topic_w[i]);
  m = block_reduce_max_256(m, sh);
  float s = 0.f;
  for (int i = tid; i < N_TOPICS; i += 256) s += __expf(topic_w[i] - m);
  s = block_reduce_sum_256(s, sh);
  float inv = 1.0f / s;
  for (int i = tid; i < N_TOPICS; i += 256) b_dt[i] = __expf(topic_w[i] - m) * inv;
  float m2 = -3.0e38f;
  for (int i = tid; i < N_WORDS; i += 256) m2 = fmaxf(m2, word_w[i]);
  m2 = block_reduce_max_256(m2, sh);
  float s2 = 0.f;
  for (int i = tid; i < N_WORDS; i += 256) s2 += __expf(word_w[i] - m2);
  s2 = block_reduce_sum_256(s2, sh);
  float inv2 = 1.0f / s2;
  for (int i = tid; i < N_WORDS; i += 256) b_tw[i] = __expf(word_w[i] - m2) * inv2;
  if (tid < 4) dscal[tid] = 0.0;
  if (tid < 2) errs[tid] = 0.f;
}

// ---------------- K = exp(-alpha * dist), optional transposed copy -----------------
__global__ __launch_bounds__(256)
void dist_exp_kernel(const float* __restrict__ A, const float* __restrict__ B,
                     const float* __restrict__ nA, const float* __restrict__ nB,
                     float* __restrict__ Kout, float* __restrict__ KoutT,
                     int nI, int nJ, float alpha) {
  __shared__ __align__(16) float As[16][64];
  __shared__ __align__(16) float Bs[16][64];
  const int i0 = blockIdx.y * 64, j0 = blockIdx.x * 64;
  const int tid = threadIdx.x;
  const int r = tid & 63, kg = tid >> 6;
  const int tx = tid & 15, ty = tid >> 4;
  float acc[4][4] = {};
  for (int k0 = 0; k0 < EDIM; k0 += 16) {
    float4 av = make_float4(0.f, 0.f, 0.f, 0.f);
    float4 bv = make_float4(0.f, 0.f, 0.f, 0.f);
    int gi = i0 + r, gj = j0 + r;
    if (gi < nI) av = *reinterpret_cast<const float4*>(&A[gi * EDIM + k0 + kg * 4]);
    if (gj < nJ) bv = *reinterpret_cast<const float4*>(&B[gj * EDIM + k0 + kg * 4]);
    As[kg * 4 + 0][r] = av.x; As[kg * 4 + 1][r] = av.y;
    As[kg * 4 + 2][r] = av.z; As[kg * 4 + 3][r] = av.w;
    Bs[kg * 4 + 0][r] = bv.x; Bs[kg * 4 + 1][r] = bv.y;
    Bs[kg * 4 + 2][r] = bv.z; Bs[kg * 4 + 3][r] = bv.w;
    __syncthreads();
#pragma unroll
    for (int kk = 0; kk < 16; ++kk) {
      float4 a4 = *reinterpret_cast<const float4*>(&As[kk][ty * 4]);
      float4 b4 = *reinterpret_cast<const float4*>(&Bs[kk][tx * 4]);
      float aa[4] = {a4.x, a4.y, a4.z, a4.w};
      float bb[4] = {b4.x, b4.y, b4.z, b4.w};
#pragma unroll
      for (int di = 0; di < 4; ++di)
#pragma unroll
        for (int dj = 0; dj < 4; ++dj) acc[di][dj] += aa[di] * bb[dj];
    }
    __syncthreads();
  }
#pragma unroll
  for (int di = 0; di < 4; ++di) {
    int gi = i0 + ty * 4 + di;
    if (gi < nI) {
      float na = nA[gi];
#pragma unroll
      for (int dj = 0; dj < 4; ++dj) {
        int gj = j0 + tx * 4 + dj;
        if (gj < nJ) {
          float val = __expf(-alpha * (na + nB[gj] - 2.f * acc[di][dj]));
          Kout[(size_t)gi * nJ + gj] = val;
          if (KoutT) KoutT[(size_t)gj * nI + gi] = val;
        }
      }
    }
  }
}

// ============== Sinkhorn DT (rows=4096 docs, cols=100 topics), iteration 1 =========
// colsum via K^T rows (coalesced), then v = b/(cs+eps)
__global__ __launch_bounds__(256)
void cs_dt_kernel(const float* __restrict__ KT, const float* __restrict__ b,
                  float* __restrict__ v) {
  __shared__ float sh[4];
  int j = blockIdx.x, tid = threadIdx.x;
  float s = 0.f;
  for (int i = tid; i < N_DOCS; i += 256) s += KT[(size_t)j * N_DOCS + i];
  s = block_reduce_sum_256(s, sh);
  if (tid == 0) v[j] = b[j] / (s * (1.0f / N_DOCS) + 1e-16f);
}

__global__ __launch_bounds__(256)
void u_dt_kernel(const float* __restrict__ Kg, const float* __restrict__ v,
                 float* __restrict__ u) {
  __shared__ float vl[N_TOPICS];
  int tid = threadIdx.x;
  if (tid < N_TOPICS) vl[tid] = v[tid];
  __syncthreads();
  int i = blockIdx.x * 256 + tid;   // 16 blocks * 256 = 4096
  float d = 0.f;
  const float* row = &Kg[(size_t)i * N_TOPICS];
#pragma unroll
  for (int j4 = 0; j4 < N_TOPICS; j4 += 4) {
    float4 kv = *reinterpret_cast<const float4*>(&row[j4]);
    d += kv.x * vl[j4] + kv.y * vl[j4 + 1] + kv.z * vl[j4 + 2] + kv.w * vl[j4 + 3];
  }
  u[i] = (1.0f / N_DOCS) / (d + 1e-16f);
}

__global__ __launch_bounds__(256)
void err_dt_kernel(const float* __restrict__ KT, const float* __restrict__ u,
                   const float* __restrict__ v, const float* __restrict__ b,
                   float* __restrict__ err) {
  __shared__ float sh[4];
  int j = blockIdx.x, tid = threadIdx.x;
  float s = 0.f;
  for (int i = tid; i < N_DOCS; i += 256) s += KT[(size_t)j * N_DOCS + i] * u[i];
  s = block_reduce_sum_256(s, sh);
  if (tid == 0) atomicAdd(err, fabsf(v[j] * s - b[j]));
}

// Remainder: only runs the loop if err > 0.005 (never on this input). Faithful.
__global__ __launch_bounds__(1024)
void rem_dt_kernel(const float* __restrict__ Kg, const float* __restrict__ KT,
                   const float* __restrict__ b, float* __restrict__ u,
                   float* __restrict__ v, const float* __restrict__ errp) {
  float err = errp[0];
  if (!(err > 0.005f)) return;
  __shared__ float u_l[N_DOCS];
  __shared__ float v_l[N_TOPICS];
  __shared__ float bl[N_TOPICS];
  __shared__ float esh;
  int tid = threadIdx.x, wave = tid >> 6, lane = tid & 63;
  for (int i = tid; i < N_DOCS; i += 1024) u_l[i] = u[i];
  if (tid < N_TOPICS) { bl[tid] = b[tid]; v_l[tid] = v[tid]; }
  __syncthreads();
  int cpt = 1;
  while (err > 0.005f && cpt < 5000) {
    for (int j = wave; j < N_TOPICS; j += 16) {
      float s = 0.f;
      for (int i = lane; i < N_DOCS; i += 64) s += KT[(size_t)j * N_DOCS + i] * u_l[i];
#pragma unroll
      for (int off = 32; off > 0; off >>= 1) s += __shfl_down(s, off, 64);
      if (lane == 0) v_l[j] = bl[j] / (s + 1e-16f);
    }
    __syncthreads();
    for (int i = tid; i < N_DOCS; i += 1024) {
      float d = 0.f;
      for (int j = 0; j < N_TOPICS; ++j) d += Kg[(size_t)i * N_TOPICS + j] * v_l[j];
      u_l[i] = (1.0f / N_DOCS) / (d + 1e-16f);
    }
    __syncthreads();
    ++cpt;
    if (cpt % 50 == 1) {
      if (tid == 0) esh = 0.f;
      __syncthreads();
      for (int j = wave; j < N_TOPICS; j += 16) {
        float s = 0.f;
        for (int i = lane; i < N_DOCS; i += 64) s += KT[(size_t)j * N_DOCS + i] * u_l[i];
#pragma unroll
        for (int off = 32; off > 0; off >>= 1) s += __shfl_down(s, off, 64);
        if (lane == 0) atomicAdd(&esh, fabsf(v_l[j] * s - bl[j]));
      }
      __syncthreads();
      err = esh;
      __syncthreads();
    }
  }
  for (int i = tid; i < N_DOCS; i += 1024) u[i] = u_l[i];
  if (tid < N_TOPICS) v[tid] = v_l[tid];
}

// ============== Sinkhorn TW (rows=100 topics, cols=10000 words), iteration 1 =======
__global__ __launch_bounds__(256)
void cs_tw_kernel(const float* __restrict__ Kg, const float* __restrict__ b,
                  float* __restrict__ v) {
  int j = blockIdx.x * 256 + threadIdx.x;   // 40 blocks
  if (j >= N_WORDS) return;
  float s = 0.f;
  for (int i = 0; i < N_TOPICS; ++i) s += Kg[(size_t)i * N_WORDS + j];
  v[j] = b[j] / (s * 0.01f + 1e-16f);
}

__global__ __launch_bounds__(256)
void u_tw_kernel(const float* __restrict__ Kg, const float* __restrict__ v,
                 float* __restrict__ u) {
  __shared__ float sh[4];
  int i = blockIdx.x, tid = threadIdx.x;   // 100 blocks
  float d = 0.f;
  const float* row = &Kg[(size_t)i * N_WORDS];
  for (int j = tid * 4; j < N_WORDS; j += 1024) {
    float4 kv = *reinterpret_cast<const float4*>(&row[j]);
    float4 vv = *reinterpret_cast<const float4*>(&v[j]);
    d += kv.x * vv.x + kv.y * vv.y + kv.z * vv.z + kv.w * vv.w;
  }
  d = block_reduce_sum_256(d, sh);
  if (tid == 0) u[i] = 0.01f / (d + 1e-16f);
}

__global__ __launch_bounds__(256)
void err_tw_kernel(const float* __restrict__ Kg, const float* __restrict__ u,
                   const float* __restrict__ v, const float* __restrict__ b,
                   float* __restrict__ err) {
  __shared__ float ul[N_TOPICS];
  __shared__ float sh[4];
  int tid = threadIdx.x;
  if (tid < N_TOPICS) ul[tid] = u[tid];
  __syncthreads();
  int j = blockIdx.x * 256 + tid;
  float e = 0.f;
  if (j < N_WORDS) {
    float s = 0.f;
    for (int i = 0; i < N_TOPICS; ++i) s += Kg[(size_t)i * N_WORDS + j] * ul[i];
    e = fabsf(v[j] * s - b[j]);
  }
  e = block_reduce_sum_256(e, sh);
  if (tid == 0) atomicAdd(err, e);
}

__global__ __launch_bounds__(1024)
void rem_tw_kernel(const float* __restrict__ Kg, const float* __restrict__ b,
                   float* __restrict__ u, float* __restrict__ v,
                   const float* __restrict__ errp) {
  float err = errp[0];
  if (!(err > 0.005f)) return;
  __shared__ float v_l[N_WORDS];
  __shared__ float bl[N_WORDS];
  __shared__ float u_l[N_TOPICS];
  __shared__ float esh;
  int tid = threadIdx.x, wave = tid >> 6, lane = tid & 63;
  for (int j = tid; j < N_WORDS; j += 1024) { v_l[j] = v[j]; bl[j] = b[j]; }
  if (tid < N_TOPICS) u_l[tid] = u[tid];
  __syncthreads();
  int cpt = 1;
  while (err > 0.005f && cpt < 5000) {
    for (int j = tid; j < N_WORDS; j += 1024) {
      float s = 0.f;
      for (int i = 0; i < N_TOPICS; ++i) s += Kg[(size_t)i * N_WORDS + j] * u_l[i];
      v_l[j] = bl[j] / (s + 1e-16f);
    }
    __syncthreads();
    for (int i = wave; i < N_TOPICS; i += 16) {
      float s = 0.f;
      for (int j = lane; j < N_WORDS; j += 64) s += Kg[(size_t)i * N_WORDS + j] * v_l[j];
#pragma unroll
      for (int off = 32; off > 0; off >>= 1) s += __shfl_down(s, off, 64);
      if (lane == 0) u_l[i] = 0.01f / (s + 1e-16f);
    }
    __syncthreads();
    ++cpt;
    if (cpt % 50 == 1) {
      if (tid == 0) esh = 0.f;
      __syncthreads();
      float e = 0.f;
      for (int j = tid; j < N_WORDS; j += 1024) {
        float s = 0.f;
        for (int i = 0; i < N_TOPICS; ++i) s += Kg[(size_t)i * N_WORDS + j] * u_l[i];
        e += fabsf(v_l[j] * s - bl[j]);
      }
      atomicAdd(&esh, e);
      __syncthreads();
      err = esh;
      __syncthreads();
    }
  }
  for (int j = tid; j < N_WORDS; j += 1024) v[j] = v_l[j];
  if (tid < N_TOPICS) u[tid] = u_l[tid];
}

// ---------------- apply: theta (bf16, K-padded) + loss_DT ---------------------------
__global__ __launch_bounds__(256)
void apply_dt_kernel(const float* __restrict__ Kg, const float* __restrict__ u,
                     const float* __restrict__ v, unsigned short* __restrict__ theta_b,
                     double* __restrict__ dscal) {
  __shared__ float sh[4];
  int idx = blockIdx.x * 256 + threadIdx.x;   // 2048 blocks -> 4096*128
  int i = idx >> 7, k = idx & 127;
  float lp = 0.f;
  unsigned short out = 0;
  if (k < N_TOPICS) {
    float kv = Kg[(size_t)i * N_TOPICS + k];
    float t = u[i] * kv * v[k];
    lp = t * (-__logf(kv) * (1.0f / 3.0f));
    out = f2bf(t * (float)N_DOCS);
  }
  theta_b[idx] = out;
  lp = block_reduce_sum_256(lp, sh);
  if (threadIdx.x == 0) atomicAdd(&dscal[0], (double)lp);
}

// ---------------- apply: beta^T (bf16, [n][k] rows, K-padded) + loss_TW -------------
__global__ __launch_bounds__(256)
void apply_tw_kernel(const float* __restrict__ Kg, const float* __restrict__ u,
                     const float* __restrict__ v, unsigned short* __restrict__ beta_bT,
                     double* __restrict__ dscal) {
  __shared__ float ul[N_TOPICS];
  __shared__ float sh[4];
  int tid = threadIdx.x;
  if (tid < N_TOPICS) ul[tid] = u[tid];
  __syncthreads();
  int n = blockIdx.x * 256 + tid;   // 40 blocks
  float lp = 0.f;
  if (n < N_WORDS) {
    float vn = v[n];
    unsigned short* dst = &beta_bT[(size_t)n * KPAD];
#pragma unroll 2
    for (int kc = 0; kc < KPAD; kc += 8) {
      unsigned short pk[8];
#pragma unroll
      for (int q = 0; q < 8; ++q) {
        int k = kc + q;
        unsigned short o = 0;
        if (k < N_TOPICS) {
          float kv = Kg[(size_t)k * N_WORDS + n];
          float t = ul[k] * kv * vn;
          lp += t * (-__logf(kv) * 0.5f);
          o = f2bf(t * (float)N_TOPICS);
        }
        pk[q] = o;
      }
      *(uint4*)&dst[kc] = *(uint4*)pk;
    }
  }
  lp = block_reduce_sum_256(lp, sh);
  if (tid == 0) atomicAdd(&dscal[1], (double)lp);
}

// ---------------- recon via bf16 MFMA, fused bow*log reduction ----------------------
#define AS_LD 136   // padded LDS leading dim (bf16 elems): 2-way conflicts only
__global__ __launch_bounds__(256)
void recon_kernel(const unsigned short* __restrict__ theta_b,
                  const unsigned short* __restrict__ beta_bT,
                  const float* __restrict__ bow, double* __restrict__ dscal) {
  __shared__ unsigned short As[128 * AS_LD];
  __shared__ unsigned short Bs[128 * AS_LD];
  __shared__ float sh4[4];
  const int tid = threadIdx.x;
  const int c0 = blockIdx.x * 128, r0 = blockIdx.y * 128;
#pragma unroll
  for (int pass = 0; pass < 8; ++pass) {
    int idx = pass * 256 + tid;        // 0..2047
    int r = idx >> 4, k16 = idx & 15;
    uint4 va = *(const uint4*)&theta_b[(size_t)(r0 + r) * KPAD + k16 * 8];
    *(uint4*)&As[r * AS_LD + k16 * 8] = va;
    uint4 vb = *(const uint4*)&beta_bT[(size_t)(c0 + r) * KPAD + k16 * 8];
    *(uint4*)&Bs[r * AS_LD + k16 * 8] = vb;
  }
  __syncthreads();
  const int wave = tid >> 6, lane = tid & 63;
  const int wr = (wave >> 1) * 64, wc = (wave & 1) * 64;
  const int lm = lane & 15, q = lane >> 4;
  f32x4 acc[4][4] = {};
#pragma unroll
  for (int kc = 0; kc < 4; ++kc) {
    int k = kc * 32 + q * 8;
    bf16x8 af[4], bfr[4];
#pragma unroll
    for (int t = 0; t < 4; ++t) {
      af[t]  = *(const bf16x8*)&As[(wr + t * 16 + lm) * AS_LD + k];
      bfr[t] = *(const bf16x8*)&Bs[(wc + t * 16 + lm) * AS_LD + k];
    }
#pragma unroll
    for (int mi = 0; mi < 4; ++mi)
#pragma unroll
      for (int ni = 0; ni < 4; ++ni)
        acc[mi][ni] = __builtin_amdgcn_mfma_f32_16x16x32_bf16(af[mi], bfr[ni],
                                                              acc[mi][ni], 0, 0, 0);
  }
  float lp = 0.f;
#pragma unroll
  for (int mi = 0; mi < 4; ++mi) {
#pragma unroll
    for (int reg = 0; reg < 4; ++reg) {
      int gi = r0 + wr + mi * 16 + q * 4 + reg;
      const float* brow = &bow[(size_t)gi * N_WORDS];
#pragma unroll
      for (int ni = 0; ni < 4; ++ni) {
        int gj = c0 + wc + ni * 16 + lm;
        if (gj < N_WORDS)
          lp += brow[gj] * __logf(acc[mi][ni][reg] + 1e-12f);
      }
    }
  }
  lp = block_reduce_sum_256(lp, sh4);
  if (tid == 0) atomicAdd(&dscal[2], (double)lp);
}

// ---------------- final scalar ------------------------------------------------------
__global__ void finalize_kernel(const double* __restrict__ dscal, float* __restrict__ out) {
  out[0] = (float)(dscal[0] + dscal[1] - dscal[2] * (1.0 / N_DOCS));
}

extern "C" void kernel_launch(void* const* d_in, const int* in_sizes, int n_in,
                              void* d_out, int out_size, void* d_ws, size_t ws_size,
                              hipStream_t stream) {
  const float* bow     = (const float*)d_in[0];
  const float* docs    = (const float*)d_in[1];
  const float* words   = (const float*)d_in[2];
  const float* topics  = (const float*)d_in[3];
  const float* word_w  = (const float*)d_in[4];
  const float* topic_w = (const float*)d_in[5];
  float* out = (float*)d_out;

  double* dscal = (double*)d_ws;
  float* fws  = (float*)d_ws;
  float* errs = fws + 8;          // [0]=err_dt, [1]=err_tw
  float* Kdt  = fws + OFF_KDT;
  float* KdtT = fws + OFF_KDTT;
  float* Ktw  = fws + OFF_KTW;
  float* b_dt = fws + OFF_BDT;
  float* b_tw = fws + OFF_BTW;
  float* nd   = fws + OFF_ND;
  float* nw   = fws + OFF_NW;
  float* nt   = fws + OFF_NT;
  float* u_dt = fws + OFF_UDT;
  float* v_dt = fws + OFF_VDT;
  float* u_tw = fws + OFF_UTW;
  float* v_tw = fws + OFF_VTW;
  unsigned short* theta_b = (unsigned short*)(fws + OFF_THB);
  unsigned short* beta_bT = (unsigned short*)(fws + OFF_BTT);

  norms_kernel<<<dim3(N_DOCS + N_WORDS + N_TOPICS), dim3(64), 0, stream>>>(
      docs, words, topics, nd, nw, nt);
  prep_kernel<<<dim3(1), dim3(256), 0, stream>>>(topic_w, word_w, b_dt, b_tw, dscal, errs);
  dist_exp_kernel<<<dim3(2, 64), dim3(256), 0, stream>>>(
      docs, topics, nd, nt, Kdt, KdtT, N_DOCS, N_TOPICS, 3.0f);
  dist_exp_kernel<<<dim3(157, 2), dim3(256), 0, stream>>>(
      topics, words, nt, nw, Ktw, nullptr, N_TOPICS, N_WORDS, 2.0f);

  // Sinkhorn DT: iteration 1 fully parallel, remainder kernel exits if converged
  cs_dt_kernel<<<dim3(100), dim3(256), 0, stream>>>(KdtT, b_dt, v_dt);
  u_dt_kernel<<<dim3(16), dim3(256), 0, stream>>>(Kdt, v_dt, u_dt);
  err_dt_kernel<<<dim3(100), dim3(256), 0, stream>>>(KdtT, u_dt, v_dt, b_dt, &errs[0]);
  rem_dt_kernel<<<dim3(1), dim3(1024), 0, stream>>>(Kdt, KdtT, b_dt, u_dt, v_dt, &errs[0]);

  // Sinkhorn TW
  cs_tw_kernel<<<dim3(40), dim3(256), 0, stream>>>(Ktw, b_tw, v_tw);
  u_tw_kernel<<<dim3(100), dim3(256), 0, stream>>>(Ktw, v_tw, u_tw);
  err_tw_kernel<<<dim3(40), dim3(256), 0, stream>>>(Ktw, u_tw, v_tw, b_tw, &errs[1]);
  rem_tw_kernel<<<dim3(1), dim3(1024), 0, stream>>>(Ktw, b_tw, u_tw, v_tw, &errs[1]);

  apply_dt_kernel<<<dim3(2048), dim3(256), 0, stream>>>(Kdt, u_dt, v_dt, theta_b, dscal);
  apply_tw_kernel<<<dim3(40), dim3(256), 0, stream>>>(Ktw, u_tw, v_tw, beta_bT, dscal);

  recon_kernel<<<dim3(79, 32), dim3(256), 0, stream>>>(theta_b, beta_bT, bow, dscal);
  finalize_kernel<<<dim3(1), dim3(1), 0, stream>>>(dscal, out);

  (void)in_sizes; (void)n_in; (void)out_size; (void)ws_size;
}

// Round 3
// 481.124 us; speedup vs baseline: 1.2327x; 1.1409x over previous
//
#include <hip/hip_runtime.h>

// Problem dims (fixed by reference setup_inputs)
#define N_DOCS   4096
#define N_WORDS  10000
#define N_TOPICS 100
#define EDIM     384
#define KPAD     128       // padded inner dim for bf16 MFMA recon
#define BT_ROWS  10112     // beta^T rows allocated (79*128 grid cols)
#define RECON_BLOCKS (79 * 32)

// ---------------- workspace layout (float offsets) --------------------------------
// [0..8): 4 doubles: loss_DT, loss_TW, sum(bow*log(recon)), unused
// fws[8]: err_dt, fws[9]: err_tw, ((int*)fws)[10]: recon completion counter
#define OFF_KDT   16u                        // 4096*100 fp32
#define OFF_KDTT  (OFF_KDT  + 409600u)       // 100*4096 fp32 (transpose)
#define OFF_KTW   (OFF_KDTT + 409600u)       // 100*10000 fp32
#define OFF_BDT   (OFF_KTW  + 1000000u)      // 100 (pad 128)
#define OFF_BTW   (OFF_BDT  + 128u)          // 10000 (pad 10016)
#define OFF_ND    (OFF_BTW  + 10016u)        // 4096
#define OFF_NW    (OFF_ND   + 4096u)         // 10000 (pad 10016)
#define OFF_NT    (OFF_NW   + 10016u)        // 100 (pad 128)
#define OFF_UDT   (OFF_NT   + 128u)          // 4096
#define OFF_VDT   (OFF_UDT  + 4096u)         // 100 (pad 128)
#define OFF_UTW   (OFF_VDT  + 128u)          // 100 (pad 128)
#define OFF_VTW   (OFF_UTW  + 128u)          // 10000 (pad 10016)
#define OFF_THB   (OFF_VTW  + 10016u)        // theta bf16 4096*128 = 262144 floats
#define OFF_BTT   (OFF_THB  + 262144u)       // beta^T bf16 10112*128 = 647168 floats

typedef __attribute__((ext_vector_type(8))) short bf16x8;
typedef __attribute__((ext_vector_type(4))) float f32x4;

__device__ __forceinline__ float block_reduce_sum_256(float v, volatile float* sh) {
#pragma unroll
  for (int off = 32; off > 0; off >>= 1) v += __shfl_down(v, off, 64);
  __syncthreads();
  if ((threadIdx.x & 63) == 0) sh[threadIdx.x >> 6] = v;
  __syncthreads();
  return sh[0] + sh[1] + sh[2] + sh[3];
}

__device__ __forceinline__ float block_reduce_sum_1024(float v, volatile float* sh) {
#pragma unroll
  for (int off = 32; off > 0; off >>= 1) v += __shfl_down(v, off, 64);
  if ((threadIdx.x & 63) == 0) sh[threadIdx.x >> 6] = v;
  __syncthreads();
  if (threadIdx.x == 0) {
    float s = 0.f;
    for (int i = 0; i < 16; ++i) s += sh[i];
    sh[16] = s;
  }
  __syncthreads();
  float r = sh[16];
  __syncthreads();
  return r;
}

__device__ __forceinline__ float block_reduce_max_1024(float v, volatile float* sh) {
#pragma unroll
  for (int off = 32; off > 0; off >>= 1) v = fmaxf(v, __shfl_down(v, off, 64));
  if ((threadIdx.x & 63) == 0) sh[threadIdx.x >> 6] = v;
  __syncthreads();
  if (threadIdx.x == 0) {
    float m = sh[0];
    for (int i = 1; i < 16; ++i) m = fmaxf(m, sh[i]);
    sh[16] = m;
  }
  __syncthreads();
  float r = sh[16];
  __syncthreads();
  return r;
}

__device__ __forceinline__ unsigned short f2bf(float x) {
  union { float f; unsigned int u; } c; c.f = x;
  unsigned int r = c.u + 0x7FFF + ((c.u >> 16) & 1);   // RNE
  return (unsigned short)(r >> 16);
}

// ========== K1: norms (blocks 0..887) + softmaxes/zeroing (block 888) ==============
__global__ __launch_bounds__(1024)
void prep_norms_kernel(const float* __restrict__ docs, const float* __restrict__ words,
                       const float* __restrict__ topics,
                       const float* __restrict__ topic_w, const float* __restrict__ word_w,
                       float* __restrict__ nd, float* __restrict__ nw, float* __restrict__ nt,
                       float* __restrict__ b_dt, float* __restrict__ b_tw,
                       double* __restrict__ dscal, float* __restrict__ errs,
                       int* __restrict__ counter) {
  int tid = threadIdx.x, lane = tid & 63, wave = tid >> 6;
  if (blockIdx.x < 888) {   // row norms: 16 rows/block, one wave per row
    int row = blockIdx.x * 16 + wave;
    if (row < N_DOCS + N_WORDS + N_TOPICS) {
      const float* src; float* dst; int r;
      if (row < N_DOCS)                { src = docs;   r = row;                    dst = nd; }
      else if (row < N_DOCS + N_WORDS) { src = words;  r = row - N_DOCS;           dst = nw; }
      else                             { src = topics; r = row - N_DOCS - N_WORDS; dst = nt; }
      float s = 0.f;
#pragma unroll
      for (int k = lane; k < EDIM; k += 64) { float x = src[r * EDIM + k]; s += x * x; }
#pragma unroll
      for (int off = 32; off > 0; off >>= 1) s += __shfl_down(s, off, 64);
      if (lane == 0) dst[r] = s;
    }
    return;
  }
  // prep block
  __shared__ float sh[20];
  // topic softmax (100)
  float m = (tid < N_TOPICS) ? topic_w[tid] : -3.0e38f;
  m = block_reduce_max_1024(m, sh);
  float e = (tid < N_TOPICS) ? __expf(topic_w[tid] - m) : 0.f;
  float s = block_reduce_sum_1024(e, sh);
  if (tid < N_TOPICS) b_dt[tid] = e / s;
  // word softmax (10000), float4 vectorized
  float m2 = -3.0e38f;
  for (int i = tid * 4; i < N_WORDS; i += 4096) {
    float4 w = *reinterpret_cast<const float4*>(&word_w[i]);
    m2 = fmaxf(fmaxf(m2, fmaxf(w.x, w.y)), fmaxf(w.z, w.w));
  }
  m2 = block_reduce_max_1024(m2, sh);
  float s2 = 0.f;
  for (int i = tid * 4; i < N_WORDS; i += 4096) {
    float4 w = *reinterpret_cast<const float4*>(&word_w[i]);
    s2 += __expf(w.x - m2) + __expf(w.y - m2) + __expf(w.z - m2) + __expf(w.w - m2);
  }
  s2 = block_reduce_sum_1024(s2, sh);
  float inv2 = 1.0f / s2;
  for (int i = tid * 4; i < N_WORDS; i += 4096) {
    float4 w = *reinterpret_cast<const float4*>(&word_w[i]);
    float4 o = make_float4(__expf(w.x - m2) * inv2, __expf(w.y - m2) * inv2,
                           __expf(w.z - m2) * inv2, __expf(w.w - m2) * inv2);
    *reinterpret_cast<float4*>(&b_tw[i]) = o;
  }
  if (tid < 4) dscal[tid] = 0.0;
  if (tid < 2) errs[tid] = 0.f;
  if (tid == 0) *counter = 0;
}

// ========== K2: both distance kernels K = exp(-alpha*dist) =========================
__global__ __launch_bounds__(256)
void dist_kernel(const float* __restrict__ docs, const float* __restrict__ words,
                 const float* __restrict__ topics,
                 const float* __restrict__ nd, const float* __restrict__ nw,
                 const float* __restrict__ nt,
                 float* __restrict__ Kdt, float* __restrict__ KdtT,
                 float* __restrict__ Ktw) {
  __shared__ __align__(16) float As[16][64];
  __shared__ __align__(16) float Bs[16][64];
  const int bid = blockIdx.x;
  const float *A, *B, *nA, *nB; float *Kout, *KoutT; int nI, nJ, i0, j0; float alpha;
  if (bid < 128) {      // doc-topic: 64 i-tiles x 2 j-tiles
    A = docs; B = topics; nA = nd; nB = nt; Kout = Kdt; KoutT = KdtT;
    nI = N_DOCS; nJ = N_TOPICS; alpha = 3.0f;
    j0 = (bid & 1) * 64; i0 = (bid >> 1) * 64;
  } else {              // topic-word: 2 i-tiles x 157 j-tiles
    int b2 = bid - 128;
    A = topics; B = words; nA = nt; nB = nw; Kout = Ktw; KoutT = nullptr;
    nI = N_TOPICS; nJ = N_WORDS; alpha = 2.0f;
    i0 = (b2 & 1) * 64; j0 = (b2 >> 1) * 64;
  }
  const int tid = threadIdx.x;
  const int r = tid & 63, kg = tid >> 6;
  const int tx = tid & 15, ty = tid >> 4;
  float acc[4][4] = {};
  for (int k0 = 0; k0 < EDIM; k0 += 16) {
    float4 av = make_float4(0.f, 0.f, 0.f, 0.f);
    float4 bv = make_float4(0.f, 0.f, 0.f, 0.f);
    int gi = i0 + r, gj = j0 + r;
    if (gi < nI) av = *reinterpret_cast<const float4*>(&A[gi * EDIM + k0 + kg * 4]);
    if (gj < nJ) bv = *reinterpret_cast<const float4*>(&B[gj * EDIM + k0 + kg * 4]);
    As[kg * 4 + 0][r] = av.x; As[kg * 4 + 1][r] = av.y;
    As[kg * 4 + 2][r] = av.z; As[kg * 4 + 3][r] = av.w;
    Bs[kg * 4 + 0][r] = bv.x; Bs[kg * 4 + 1][r] = bv.y;
    Bs[kg * 4 + 2][r] = bv.z; Bs[kg * 4 + 3][r] = bv.w;
    __syncthreads();
#pragma unroll
    for (int kk = 0; kk < 16; ++kk) {
      float4 a4 = *reinterpret_cast<const float4*>(&As[kk][ty * 4]);
      float4 b4 = *reinterpret_cast<const float4*>(&Bs[kk][tx * 4]);
      float aa[4] = {a4.x, a4.y, a4.z, a4.w};
      float bb[4] = {b4.x, b4.y, b4.z, b4.w};
#pragma unroll
      for (int di = 0; di < 4; ++di)
#pragma unroll
        for (int dj = 0; dj < 4; ++dj) acc[di][dj] += aa[di] * bb[dj];
    }
    __syncthreads();
  }
#pragma unroll
  for (int di = 0; di < 4; ++di) {
    int gi = i0 + ty * 4 + di;
    if (gi < nI) {
      float na = nA[gi];
#pragma unroll
      for (int dj = 0; dj < 4; ++dj) {
        int gj = j0 + tx * 4 + dj;
        if (gj < nJ) {
          float val = __expf(-alpha * (na + nB[gj] - 2.f * acc[di][dj]));
          Kout[(size_t)gi * nJ + gj] = val;
          if (KoutT) KoutT[(size_t)gj * nI + gi] = val;
        }
      }
    }
  }
}

// ========== K3: colsum -> v for both transports ====================================
__global__ __launch_bounds__(256)
void cs_kernel(const float* __restrict__ KdtT, const float* __restrict__ b_dt,
               float* __restrict__ v_dt,
               const float* __restrict__ Ktw, const float* __restrict__ b_tw,
               float* __restrict__ v_tw) {
  __shared__ float sh[4];
  const int tid = threadIdx.x;
  if (blockIdx.x < 100) {          // DT: one block per topic column
    int j = blockIdx.x;
    float s = 0.f;
#pragma unroll 8
    for (int i = tid; i < N_DOCS; i += 256) s += KdtT[(size_t)j * N_DOCS + i];
    s = block_reduce_sum_256(s, sh);
    if (tid == 0) v_dt[j] = b_dt[j] / (s * (1.0f / N_DOCS) + 1e-16f);
  } else {                          // TW: one thread per word column
    int j = (blockIdx.x - 100) * 256 + tid;
    if (j < N_WORDS) {
      float s = 0.f;
#pragma unroll 10
      for (int i = 0; i < N_TOPICS; ++i) s += Ktw[(size_t)i * N_WORDS + j];
      v_tw[j] = b_tw[j] / (s * 0.01f + 1e-16f);
    }
  }
}

// ========== K4: rowdot -> u for both transports ====================================
__global__ __launch_bounds__(256)
void u_kernel(const float* __restrict__ Kdt, const float* __restrict__ v_dt,
              float* __restrict__ u_dt,
              const float* __restrict__ Ktw, const float* __restrict__ v_tw,
              float* __restrict__ u_tw) {
  __shared__ float vl[N_TOPICS];
  __shared__ float sh[4];
  const int tid = threadIdx.x;
  if (blockIdx.x < 16) {            // DT: one thread per doc row
    if (tid < N_TOPICS) vl[tid] = v_dt[tid];
    __syncthreads();
    int i = blockIdx.x * 256 + tid;
    float d = 0.f;
    const float* row = &Kdt[(size_t)i * N_TOPICS];
#pragma unroll
    for (int j4 = 0; j4 < N_TOPICS; j4 += 4) {
      float4 kv = *reinterpret_cast<const float4*>(&row[j4]);
      d += kv.x * vl[j4] + kv.y * vl[j4 + 1] + kv.z * vl[j4 + 2] + kv.w * vl[j4 + 3];
    }
    u_dt[i] = (1.0f / N_DOCS) / (d + 1e-16f);
  } else {                          // TW: one block per topic row
    int i = blockIdx.x - 16;
    float d = 0.f;
    const float* row = &Ktw[(size_t)i * N_WORDS];
    for (int j = tid * 4; j < N_WORDS; j += 1024) {
      float4 kv = *reinterpret_cast<const float4*>(&row[j]);
      float4 vv = *reinterpret_cast<const float4*>(&v_tw[j]);
      d += kv.x * vv.x + kv.y * vv.y + kv.z * vv.z + kv.w * vv.w;
    }
    d = block_reduce_sum_256(d, sh);
    if (tid == 0) u_tw[i] = 0.01f / (d + 1e-16f);
  }
}

// ========== K5: convergence error for both transports ==============================
__global__ __launch_bounds__(256)
void err_kernel(const float* __restrict__ KdtT, const float* __restrict__ u_dt,
                const float* __restrict__ v_dt, const float* __restrict__ b_dt,
                const float* __restrict__ Ktw, const float* __restrict__ u_tw,
                const float* __restrict__ v_tw, const float* __restrict__ b_tw,
                float* __restrict__ errs) {
  __shared__ float sh[4];
  __shared__ float ul[N_TOPICS];
  const int tid = threadIdx.x;
  if (blockIdx.x < 100) {
    int j = blockIdx.x;
    float s = 0.f;
#pragma unroll 8
    for (int i = tid; i < N_DOCS; i += 256) s += KdtT[(size_t)j * N_DOCS + i] * u_dt[i];
    s = block_reduce_sum_256(s, sh);
    if (tid == 0) atomicAdd(&errs[0], fabsf(v_dt[j] * s - b_dt[j]));
  } else {
    if (tid < N_TOPICS) ul[tid] = u_tw[tid];
    __syncthreads();
    int j = (blockIdx.x - 100) * 256 + tid;
    float e = 0.f;
    if (j < N_WORDS) {
      float s = 0.f;
#pragma unroll 10
      for (int i = 0; i < N_TOPICS; ++i) s += Ktw[(size_t)i * N_WORDS + j] * ul[i];
      e = fabsf(v_tw[j] * s - b_tw[j]);
    }
    e = block_reduce_sum_256(e, sh);
    if (tid == 0) atomicAdd(&errs[1], e);
  }
}

// ========== K6: faithful remainder loops (exit immediately when converged) =========
__global__ __launch_bounds__(1024)
void rem_kernel(const float* __restrict__ Kdt, const float* __restrict__ KdtT,
                const float* __restrict__ b_dt, float* __restrict__ u_dt,
                float* __restrict__ v_dt,
                const float* __restrict__ Ktw, const float* __restrict__ b_tw,
                float* __restrict__ u_tw, float* __restrict__ v_tw,
                const float* __restrict__ errs) {
  __shared__ float rsm[20104];     // 80.4 KB, partitioned per branch
  const int tid = threadIdx.x, wave = tid >> 6, lane = tid & 63;
  if (blockIdx.x == 0) {           // DT remainder
    float err = errs[0];
    if (!(err > 0.005f)) return;
    float* u_l = rsm; float* v_l = rsm + 4096; float* bl = rsm + 4196; float* esh = rsm + 4296;
    for (int i = tid; i < N_DOCS; i += 1024) u_l[i] = u_dt[i];
    if (tid < N_TOPICS) { bl[tid] = b_dt[tid]; v_l[tid] = v_dt[tid]; }
    __syncthreads();
    int cpt = 1;
    while (err > 0.005f && cpt < 5000) {
      for (int j = wave; j < N_TOPICS; j += 16) {
        float s = 0.f;
        for (int i = lane; i < N_DOCS; i += 64) s += KdtT[(size_t)j * N_DOCS + i] * u_l[i];
#pragma unroll
        for (int off = 32; off > 0; off >>= 1) s += __shfl_down(s, off, 64);
        if (lane == 0) v_l[j] = bl[j] / (s + 1e-16f);
      }
      __syncthreads();
      for (int i = tid; i < N_DOCS; i += 1024) {
        float d = 0.f;
        for (int j = 0; j < N_TOPICS; ++j) d += Kdt[(size_t)i * N_TOPICS + j] * v_l[j];
        u_l[i] = (1.0f / N_DOCS) / (d + 1e-16f);
      }
      __syncthreads();
      ++cpt;
      if (cpt % 50 == 1) {
        if (tid == 0) *esh = 0.f;
        __syncthreads();
        for (int j = wave; j < N_TOPICS; j += 16) {
          float s = 0.f;
          for (int i = lane; i < N_DOCS; i += 64) s += KdtT[(size_t)j * N_DOCS + i] * u_l[i];
#pragma unroll
          for (int off = 32; off > 0; off >>= 1) s += __shfl_down(s, off, 64);
          if (lane == 0) atomicAdd(esh, fabsf(v_l[j] * s - bl[j]));
        }
        __syncthreads();
        err = *esh;
        __syncthreads();
      }
    }
    for (int i = tid; i < N_DOCS; i += 1024) u_dt[i] = u_l[i];
    if (tid < N_TOPICS) v_dt[tid] = v_l[tid];
  } else {                          // TW remainder
    float err = errs[1];
    if (!(err > 0.005f)) return;
    float* v_l = rsm; float* bl = rsm + 10000; float* u_l = rsm + 20000; float* esh = rsm + 20100;
    for (int j = tid; j < N_WORDS; j += 1024) { v_l[j] = v_tw[j]; bl[j] = b_tw[j]; }
    if (tid < N_TOPICS) u_l[tid] = u_tw[tid];
    __syncthreads();
    int cpt = 1;
    while (err > 0.005f && cpt < 5000) {
      for (int j = tid; j < N_WORDS; j += 1024) {
        float s = 0.f;
        for (int i = 0; i < N_TOPICS; ++i) s += Ktw[(size_t)i * N_WORDS + j] * u_l[i];
        v_l[j] = bl[j] / (s + 1e-16f);
      }
      __syncthreads();
      for (int i = wave; i < N_TOPICS; i += 16) {
        float s = 0.f;
        for (int j = lane; j < N_WORDS; j += 64) s += Ktw[(size_t)i * N_WORDS + j] * v_l[j];
#pragma unroll
        for (int off = 32; off > 0; off >>= 1) s += __shfl_down(s, off, 64);
        if (lane == 0) u_l[i] = 0.01f / (s + 1e-16f);
      }
      __syncthreads();
      ++cpt;
      if (cpt % 50 == 1) {
        if (tid == 0) *esh = 0.f;
        __syncthreads();
        float e = 0.f;
        for (int j = tid; j < N_WORDS; j += 1024) {
          float s = 0.f;
          for (int i = 0; i < N_TOPICS; ++i) s += Ktw[(size_t)i * N_WORDS + j] * u_l[i];
          e += fabsf(v_l[j] * s - bl[j]);
        }
        atomicAdd(esh, e);
        __syncthreads();
        err = *esh;
        __syncthreads();
      }
    }
    for (int j = tid; j < N_WORDS; j += 1024) v_tw[j] = v_l[j];
    if (tid < N_TOPICS) u_tw[tid] = u_l[tid];
  }
}

// ========== K7: theta/beta^T (bf16, K-padded) + transport losses ===================
__global__ __launch_bounds__(256)
void apply_kernel(const float* __restrict__ Kdt, const float* __restrict__ u_dt,
                  const float* __restrict__ v_dt,
                  const float* __restrict__ Ktw, const float* __restrict__ u_tw,
                  const float* __restrict__ v_tw,
                  unsigned short* __restrict__ theta_b, unsigned short* __restrict__ beta_bT,
                  double* __restrict__ dscal) {
  __shared__ float sh[4];
  __shared__ float ul[N_TOPICS];
  const int tid = threadIdx.x;
  if (blockIdx.x < 2048) {          // theta: 4096*128 elements
    int idx = blockIdx.x * 256 + tid;
    int i = idx >> 7, k = idx & 127;
    float lp = 0.f;
    unsigned short o = 0;
    if (k < N_TOPICS) {
      float kv = Kdt[(size_t)i * N_TOPICS + k];
      float t = u_dt[i] * kv * v_dt[k];
      lp = t * (-__logf(kv) * (1.0f / 3.0f));
      o = f2bf(t * (float)N_DOCS);
    }
    theta_b[idx] = o;
    lp = block_reduce_sum_256(lp, sh);
    if (tid == 0) atomicAdd(&dscal[0], (double)lp);
  } else {                          // beta^T rows
    if (tid < N_TOPICS) ul[tid] = u_tw[tid];
    __syncthreads();
    int n = (blockIdx.x - 2048) * 256 + tid;
    float lp = 0.f;
    if (n < N_WORDS) {
      float vn = v_tw[n];
      unsigned short* dst = &beta_bT[(size_t)n * KPAD];
#pragma unroll 2
      for (int kc = 0; kc < KPAD; kc += 8) {
        unsigned short pk[8];
#pragma unroll
        for (int q = 0; q < 8; ++q) {
          int k = kc + q;
          unsigned short o = 0;
          if (k < N_TOPICS) {
            float kv = Ktw[(size_t)k * N_WORDS + n];
            float t = ul[k] * kv * vn;
            lp += t * (-__logf(kv) * 0.5f);
            o = f2bf(t * (float)N_TOPICS);
          }
          pk[q] = o;
        }
        *(uint4*)&dst[kc] = *(uint4*)pk;
      }
    } else if (n < BT_ROWS) {       // zero the pad rows so recon stays clean
      unsigned short* dst = &beta_bT[(size_t)n * KPAD];
      uint4 z = make_uint4(0, 0, 0, 0);
#pragma unroll
      for (int kc = 0; kc < KPAD; kc += 8) *(uint4*)&dst[kc] = z;
    }
    lp = block_reduce_sum_256(lp, sh);
    if (tid == 0) atomicAdd(&dscal[1], (double)lp);
  }
}

// ========== K8: recon via bf16 MFMA + LDS-transposed coalesced bow epilogue ========
#define AS_LD 136   // staging LD (bf16): 2-way conflicts only
#define CLD   132   // acc tile LD (fp32): float4-aligned, 2-way conflicts only
__global__ __launch_bounds__(256)
void recon_kernel(const unsigned short* __restrict__ theta_b,
                  const unsigned short* __restrict__ beta_bT,
                  const float* __restrict__ bow, double* __restrict__ dscal,
                  int* __restrict__ counter, float* __restrict__ out) {
  __shared__ __align__(16) char smem[128 * AS_LD * 2 * 2];  // 69632 B, reused for C tile
  __shared__ float sh4[4];
  unsigned short* As = (unsigned short*)smem;
  unsigned short* Bs = As + 128 * AS_LD;
  float* C = (float*)smem;          // 128 x CLD fp32 = 67584 B <= 69632
  const int tid = threadIdx.x;
  const int c0 = blockIdx.x * 128, r0 = blockIdx.y * 128;
#pragma unroll
  for (int pass = 0; pass < 8; ++pass) {
    int idx = pass * 256 + tid;     // 0..2047
    int r = idx >> 4, k16 = idx & 15;
    *(uint4*)&As[r * AS_LD + k16 * 8] = *(const uint4*)&theta_b[(size_t)(r0 + r) * KPAD + k16 * 8];
    *(uint4*)&Bs[r * AS_LD + k16 * 8] = *(const uint4*)&beta_bT[(size_t)(c0 + r) * KPAD + k16 * 8];
  }
  __syncthreads();
  const int wave = tid >> 6, lane = tid & 63;
  const int wr = (wave >> 1) * 64, wc = (wave & 1) * 64;
  const int lm = lane & 15, q = lane >> 4;
  f32x4 acc[4][4] = {};
#pragma unroll
  for (int kc = 0; kc < 4; ++kc) {
    int k = kc * 32 + q * 8;
    bf16x8 af[4], bfr[4];
#pragma unroll
    for (int t = 0; t < 4; ++t) {
      af[t]  = *(const bf16x8*)&As[(wr + t * 16 + lm) * AS_LD + k];
      bfr[t] = *(const bf16x8*)&Bs[(wc + t * 16 + lm) * AS_LD + k];
    }
#pragma unroll
    for (int mi = 0; mi < 4; ++mi)
#pragma unroll
      for (int ni = 0; ni < 4; ++ni)
        acc[mi][ni] = __builtin_amdgcn_mfma_f32_16x16x32_bf16(af[mi], bfr[ni],
                                                              acc[mi][ni], 0, 0, 0);
  }
  __syncthreads();                  // A/B fragments consumed; safe to overwrite smem
  // scatter acc (MFMA C layout) into fp32 tile: 2-way bank aliasing only
#pragma unroll
  for (int mi = 0; mi < 4; ++mi)
#pragma unroll
    for (int ni = 0; ni < 4; ++ni)
#pragma unroll
      for (int reg = 0; reg < 4; ++reg) {
        int row = wr + mi * 16 + q * 4 + reg;
        int col = wc + ni * 16 + lm;
        C[row * CLD + col] = acc[mi][ni][reg];
      }
  __syncthreads();
  // coalesced float4 bow read: wave covers 2 rows x 512B contiguous
  float lp = 0.f;
  const int c4 = tid & 31;          // float4 column 0..31
  const int rb = tid >> 5;          // row base 0..7
  const int gj0 = c0 + c4 * 4;
  if (gj0 < N_WORDS) {              // N_WORDS % 4 == 0 -> full float4 or nothing
#pragma unroll
    for (int it = 0; it < 16; ++it) {
      int row = rb + it * 8;
      float4 bw = *reinterpret_cast<const float4*>(&bow[(size_t)(r0 + row) * N_WORDS + gj0]);
      float4 rc = *reinterpret_cast<const float4*>(&C[row * CLD + c4 * 4]);
      lp += bw.x * __logf(rc.x + 1e-12f) + bw.y * __logf(rc.y + 1e-12f)
          + bw.z * __logf(rc.z + 1e-12f) + bw.w * __logf(rc.w + 1e-12f);
    }
  }
  lp = block_reduce_sum_256(lp, sh4);
  if (tid == 0) {
    atomicAdd(&dscal[2], (double)lp);
    __threadfence();
    int done = atomicAdd(counter, 1);
    if (done == RECON_BLOCKS - 1) { // last block finalizes
      double s2 = atomicAdd(&dscal[2], 0.0);
      double s0 = atomicAdd(&dscal[0], 0.0);
      double s1 = atomicAdd(&dscal[1], 0.0);
      out[0] = (float)(s0 + s1 - s2 * (1.0 / N_DOCS));
    }
  }
}

extern "C" void kernel_launch(void* const* d_in, const int* in_sizes, int n_in,
                              void* d_out, int out_size, void* d_ws, size_t ws_size,
                              hipStream_t stream) {
  const float* bow     = (const float*)d_in[0];
  const float* docs    = (const float*)d_in[1];
  const float* words   = (const float*)d_in[2];
  const float* topics  = (const float*)d_in[3];
  const float* word_w  = (const float*)d_in[4];
  const float* topic_w = (const float*)d_in[5];
  float* out = (float*)d_out;

  double* dscal = (double*)d_ws;
  float* fws  = (float*)d_ws;
  float* errs = fws + 8;
  int* counter = ((int*)d_ws) + 10;
  float* Kdt  = fws + OFF_KDT;
  float* KdtT = fws + OFF_KDTT;
  float* Ktw  = fws + OFF_KTW;
  float* b_dt = fws + OFF_BDT;
  float* b_tw = fws + OFF_BTW;
  float* nd   = fws + OFF_ND;
  float* nw   = fws + OFF_NW;
  float* nt   = fws + OFF_NT;
  float* u_dt = fws + OFF_UDT;
  float* v_dt = fws + OFF_VDT;
  float* u_tw = fws + OFF_UTW;
  float* v_tw = fws + OFF_VTW;
  unsigned short* theta_b = (unsigned short*)(fws + OFF_THB);
  unsigned short* beta_bT = (unsigned short*)(fws + OFF_BTT);

  prep_norms_kernel<<<dim3(889), dim3(1024), 0, stream>>>(
      docs, words, topics, topic_w, word_w, nd, nw, nt, b_dt, b_tw, dscal, errs, counter);
  dist_kernel<<<dim3(442), dim3(256), 0, stream>>>(
      docs, words, topics, nd, nw, nt, Kdt, KdtT, Ktw);
  cs_kernel<<<dim3(140), dim3(256), 0, stream>>>(KdtT, b_dt, v_dt, Ktw, b_tw, v_tw);
  u_kernel<<<dim3(116), dim3(256), 0, stream>>>(Kdt, v_dt, u_dt, Ktw, v_tw, u_tw);
  err_kernel<<<dim3(140), dim3(256), 0, stream>>>(
      KdtT, u_dt, v_dt, b_dt, Ktw, u_tw, v_tw, b_tw, errs);
  rem_kernel<<<dim3(2), dim3(1024), 0, stream>>>(
      Kdt, KdtT, b_dt, u_dt, v_dt, Ktw, b_tw, u_tw, v_tw, errs);
  apply_kernel<<<dim3(2088), dim3(256), 0, stream>>>(
      Kdt, u_dt, v_dt, Ktw, u_tw, v_tw, theta_b, beta_bT, dscal);
  recon_kernel<<<dim3(79, 32), dim3(256), 0, stream>>>(
      theta_b, beta_bT, bow, dscal, counter, out);

  (void)in_sizes; (void)n_in; (void)out_size; (void)ws_size;
}